// Round 9
// baseline (607.142 us; speedup 1.0000x reference)
//
#include <hip/hip_runtime.h>
#include <hip/hip_bf16.h>

// nGPT-style transformer layer, MI355X. Round 8: attn exp2-fold (log2e into Q
// scale, bias into QK mfma C-init) + setprio; 256^2 gemm 4-phase barrier-lock;
// bf16 tbuf/t2. B=4 T=2048 dm=1024 H=16 di=64.
//
// Workspace arena (peak 210 MiB). Aliasing is ORDER-SENSITIVE; launch order in
// kernel_launch is the contract.

#define B_   4
#define T_   2048
#define DM   1024
#define H_   16
#define DI   64
#define NROW (B_ * T_)   // 8192

using bf16 = __hip_bfloat16;
typedef __attribute__((ext_vector_type(8))) short bfrag;   // 8 bf16 (4 VGPR)
typedef __attribute__((ext_vector_type(4))) float f4;

#define EXPB 46.166241f   // 32 * log2(e): sdpa-scale x log2e, folded into Q

__device__ __forceinline__ float ldf(const float* p) { return *p; }
__device__ __forceinline__ float ldf(const bf16* p)  { return __bfloat162float(*p); }
__device__ __forceinline__ void  stf(float* p, float v) { *p = v; }
__device__ __forceinline__ void  stf(bf16* p, float v)  { *p = __float2bfloat16(v); }

__device__ __forceinline__ unsigned short bfbits(float a) {
    bf16 h = __float2bfloat16(a);
    return __builtin_bit_cast(unsigned short, h);
}
__device__ __forceinline__ unsigned pk2(float a, float b) {
    return (unsigned)bfbits(a) | ((unsigned)bfbits(b) << 16);
}

__device__ __forceinline__ float wave_sum(float v) {
#pragma unroll
    for (int off = 32; off; off >>= 1) v += __shfl_xor(v, off, 64);
    return v;
}

__device__ __forceinline__ float block_sum(float v) {
    __shared__ float sm[4];
    int lane = threadIdx.x & 63, w = threadIdx.x >> 6;
    v = wave_sum(v);
    __syncthreads();
    if (lane == 0) sm[w] = v;
    __syncthreads();
    return sm[0] + sm[1] + sm[2] + sm[3];
}

// async global->LDS, 16B per lane; LDS dest = wave-uniform base + lane*16
typedef __attribute__((address_space(1))) const void g_void;
typedef __attribute__((address_space(3))) void l_void;
__device__ __forceinline__ void gl_lds(const void* g, void* l) {
    __builtin_amdgcn_global_load_lds((g_void*)g, (l_void*)l, 16, 0, 0);
}

// ---------------------------------------------------------------------------
// f32 -> bf16 convert, 8 elems/thread. n must be a multiple of 2048.
// ---------------------------------------------------------------------------
__global__ __launch_bounds__(256)
void f32_to_bf16_k(const float* __restrict__ in, bf16* __restrict__ out, long n)
{
    long i = ((long)blockIdx.x * 256 + threadIdx.x) * 8;
    if (i >= n) return;
    float4 a = *(const float4*)(in + i);
    float4 b = *(const float4*)(in + i + 4);
    union { bfrag f; unsigned u[4]; } o;
    o.u[0] = pk2(a.x, a.y); o.u[1] = pk2(a.z, a.w);
    o.u[2] = pk2(b.x, b.y); o.u[3] = pk2(b.z, b.w);
    *(bfrag*)(out + i) = o.f;
}

// ---------------------------------------------------------------------------
// C = A * B^T, 128x128 tile, BK=32, 4 waves, m97 structure (N=1024 GEMMs).
// ---------------------------------------------------------------------------
template <typename TC>
__global__ __launch_bounds__(256)
void gemm_bf16(const bf16* __restrict__ A, const bf16* __restrict__ Bm,
               TC* __restrict__ C, int M, int N, int K)
{
    __shared__ bf16 lds[2][2][128 * 32];   // [buf][A|B][row*32+k]
    const int tid  = threadIdx.x;
    const int w    = tid >> 6, lane = tid & 63;
    const int g    = lane >> 4, c = lane & 15;
    const int m0   = blockIdx.y * 128, n0 = blockIdx.x * 128;
    const int wm   = w >> 1, wn = w & 1;

    const int srow = (lane >> 2);        // 0..15 within chunk
    const int skc  = 8 * (lane & 3);     // k elem offset 0,8,16,24

    f4 acc[4][4] = {{{0,0,0,0}}};

    const int NT = K >> 5;               // K/32 steps

#pragma unroll
    for (int q = 0; q < 2; q++) {
        int cidx = w * 2 + q;            // 0..7, covers rows [16*cidx,+16)
        int row  = 16 * cidx + srow;
        gl_lds(A + (long)(m0 + row) * K + skc, &lds[0][0][cidx * 512]);
        gl_lds(Bm + (long)(n0 + row) * K + skc, &lds[0][1][cidx * 512]);
    }
    __syncthreads();

    for (int t = 0; t < NT; t++) {
        int cur = t & 1;
        if (t + 1 < NT) {
            int k0 = (t + 1) << 5;
#pragma unroll
            for (int q = 0; q < 2; q++) {
                int cidx = w * 2 + q;
                int row  = 16 * cidx + srow;
                gl_lds(A + (long)(m0 + row) * K + k0 + skc, &lds[cur ^ 1][0][cidx * 512]);
                gl_lds(Bm + (long)(n0 + row) * K + k0 + skc, &lds[cur ^ 1][1][cidx * 512]);
            }
        }
        const bf16* bufA = &lds[cur][0][0];
        const bf16* bufB = &lds[cur][1][0];
        bfrag af[4], bb[4];
#pragma unroll
        for (int mi = 0; mi < 4; mi++)
            af[mi] = *(const bfrag*)(bufA + (64 * wm + 16 * mi + c) * 32 + 8 * g);
#pragma unroll
        for (int ni = 0; ni < 4; ni++)
            bb[ni] = *(const bfrag*)(bufB + (64 * wn + 16 * ni + c) * 32 + 8 * g);
#pragma unroll
        for (int mi = 0; mi < 4; mi++)
#pragma unroll
            for (int ni = 0; ni < 4; ni++)
                acc[mi][ni] = __builtin_amdgcn_mfma_f32_16x16x32_bf16(
                    af[mi], bb[ni], acc[mi][ni], 0, 0, 0);
        __syncthreads();
    }

#pragma unroll
    for (int mi = 0; mi < 4; mi++)
#pragma unroll
        for (int ni = 0; ni < 4; ni++) {
            long row = m0 + 64 * wm + 16 * mi + 4 * g;
            long col = n0 + 64 * wn + 16 * ni + c;
#pragma unroll
            for (int r = 0; r < 4; r++)
                stf(&C[(row + r) * N + col], acc[mi][ni][r]);
        }
}

// ---------------------------------------------------------------------------
// C = A * B^T, 256x256 tile, BK=64, 8 waves, 128KB LDS dbuf, 2-tile prefetch.
// Round 8: 4-phase barrier-locked schedule (m201 pattern): barrier pairs
// around each MFMA cluster; counted vmcnt(8); sched_barrier pinning.
// Buffer lifetimes identical to round 7 (barriers only added).
// ---------------------------------------------------------------------------
template <typename TC>
__global__ __launch_bounds__(512, 2)
void gemm_bf16_256(const bf16* __restrict__ A, const bf16* __restrict__ Bm,
                   TC* __restrict__ C, int M, int N, int K)
{
    __shared__ bf16 lds[2][2][256 * 64];   // 128 KiB
    const int tid  = threadIdx.x;
    const int w    = tid >> 6, lane = tid & 63;
    const int g    = lane >> 4, c = lane & 15;
    const int m0   = blockIdx.y * 256, n0 = blockIdx.x * 256;
    const int wm   = w & 1, wn = w >> 1;          // 2M x 4N wave grid
    const int srow8 = lane >> 3;                  // 0..7
    const int swz   = 8 * ((lane & 7) ^ srow8);   // pre-swizzled source chunk
    const int cx    = c & 7;

    f4 acc[8][4] = {{{0,0,0,0}}};

    const int NT = K >> 6;

    auto STAGE = [&](int buf, int t) {
        int k0 = t << 6;
#pragma unroll
        for (int i = 0; i < 4; i++) {
            int rb = w * 32 + i * 8;              // 8 rows per gl_lds
            gl_lds(A  + (long)(m0 + rb + srow8) * K + k0 + swz, &lds[buf][0][rb * 64]);
            gl_lds(Bm + (long)(n0 + rb + srow8) * K + k0 + swz, &lds[buf][1][rb * 64]);
        }
    };

    STAGE(0, 0);
    STAGE(1, 1);
    asm volatile("s_waitcnt vmcnt(8)" ::: "memory");
    __builtin_amdgcn_s_barrier();

    for (int t = 0; t < NT; t++) {
        const bf16* bufA = &lds[t & 1][0][0];
        const bf16* bufB = &lds[t & 1][1][0];

        // phase 1: issue a0/b0 ds_reads, phase-lock, MFMA cluster 0
        bfrag a0[4][2], b0[4][2];
#pragma unroll
        for (int mi = 0; mi < 4; mi++)
#pragma unroll
            for (int kk = 0; kk < 2; kk++)
                a0[mi][kk] = *(const bfrag*)(bufA + (wm * 128 + mi * 16 + c) * 64
                                                  + 8 * ((4 * kk + g) ^ cx));
#pragma unroll
        for (int ni = 0; ni < 4; ni++)
#pragma unroll
            for (int kk = 0; kk < 2; kk++)
                b0[ni][kk] = *(const bfrag*)(bufB + (wn * 64 + ni * 16 + c) * 64
                                                  + 8 * ((4 * kk + g) ^ cx));
        __builtin_amdgcn_sched_barrier(0);
        __builtin_amdgcn_s_barrier();
        asm volatile("s_waitcnt lgkmcnt(0)" ::: "memory");
        __builtin_amdgcn_sched_barrier(0);
        __builtin_amdgcn_s_setprio(1);
#pragma unroll
        for (int mi = 0; mi < 4; mi++)
#pragma unroll
            for (int ni = 0; ni < 4; ni++) {
                acc[mi][ni] = __builtin_amdgcn_mfma_f32_16x16x32_bf16(
                    a0[mi][0], b0[ni][0], acc[mi][ni], 0, 0, 0);
                acc[mi][ni] = __builtin_amdgcn_mfma_f32_16x16x32_bf16(
                    a0[mi][1], b0[ni][1], acc[mi][ni], 0, 0, 0);
            }
        __builtin_amdgcn_s_setprio(0);
        __builtin_amdgcn_s_barrier();

        // phase 2: issue a1 ds_reads, phase-lock, MFMA cluster 1
        bfrag a1[4][2];
#pragma unroll
        for (int mi = 0; mi < 4; mi++)
#pragma unroll
            for (int kk = 0; kk < 2; kk++)
                a1[mi][kk] = *(const bfrag*)(bufA + (wm * 128 + (mi + 4) * 16 + c) * 64
                                                  + 8 * ((4 * kk + g) ^ cx));
        asm volatile("s_waitcnt lgkmcnt(0)" ::: "memory");
        __builtin_amdgcn_sched_barrier(0);
        __builtin_amdgcn_s_setprio(1);
#pragma unroll
        for (int mi = 0; mi < 4; mi++)
#pragma unroll
            for (int ni = 0; ni < 4; ni++) {
                acc[mi + 4][ni] = __builtin_amdgcn_mfma_f32_16x16x32_bf16(
                    a1[mi][0], b0[ni][0], acc[mi + 4][ni], 0, 0, 0);
                acc[mi + 4][ni] = __builtin_amdgcn_mfma_f32_16x16x32_bf16(
                    a1[mi][1], b0[ni][1], acc[mi + 4][ni], 0, 0, 0);
            }
        __builtin_amdgcn_s_setprio(0);
        __builtin_amdgcn_s_barrier();

        // phase 3: refill freed buffer, counted drain (tile t+1 landed)
        if (t + 2 < NT) {
            STAGE(t & 1, t + 2);
            asm volatile("s_waitcnt vmcnt(8)" ::: "memory");
        } else if (t + 1 < NT) {
            asm volatile("s_waitcnt vmcnt(0)" ::: "memory");
        }
        __builtin_amdgcn_s_barrier();
    }

#pragma unroll
    for (int mi = 0; mi < 8; mi++)
#pragma unroll
        for (int ni = 0; ni < 4; ni++) {
            long row = m0 + wm * 128 + mi * 16 + 4 * g;
            long col = n0 + wn * 64 + ni * 16 + c;
#pragma unroll
            for (int r = 0; r < 4; r++)
                stf(&C[(row + r) * N + col], acc[mi][ni][r]);
        }
}

// ---------------------------------------------------------------------------
// RoPE + per-row L2 norm + sqk*sqrt(dm); QKVb bf16 layout [row][h*192+e].
// Qb additionally carries sdpa sqrt(dm)=32 AND log2e (exp2 path in attn).
// ---------------------------------------------------------------------------
__global__ __launch_bounds__(256)
void rope_norm_qk(const bf16* __restrict__ QKVb, const float* __restrict__ sqk,
                  bf16* __restrict__ Qb, bf16* __restrict__ Kb, bf16* __restrict__ Vt)
{
    int gw   = (blockIdx.x * 256 + threadIdx.x) >> 6;   // 0 .. H*NROW-1
    int lane = threadIdx.x & 63;
    int h = gw / NROW, row = gw % NROW, t = row % T_, b = row / T_;

    const bf16* base = QKVb + (long)row * 3072 + h * 192;
    float q = __bfloat162float(base[lane]);
    float k = __bfloat162float(base[64 + lane]);
    bf16  v = base[128 + lane];

    int   j   = lane & 31;
    float inv = expf(-(float)j * (9.210340371976184f / 32.f));  // 10000^(-j/32)
    float ang = (float)t * inv;
    float s = sinf(ang), cc = cosf(ang);

    float qp = __shfl_xor(q, 32, 64);
    float kp = __shfl_xor(k, 32, 64);
    float sgn = (lane < 32) ? -1.f : 1.f;
    float qr = q * cc + sgn * qp * s;
    float kr = k * cc + sgn * kp * s;

    float qs = wave_sum(qr * qr);
    float ks = wave_sum(kr * kr);
    float se = sqk[h * 64 + lane] * 32.f;   // sqk * sqrt(dm)

    long idx = ((long)h * NROW + row) * 64 + lane;
    Qb[idx] = __float2bfloat16(qr * rsqrtf(qs) * se * EXPB);  // 32*log2e folded
    Kb[idx] = __float2bfloat16(kr * rsqrtf(ks) * se);
    Vt[((long)(h * B_ + b) * 64 + lane) * T_ + t] = v;
}

// ---------------------------------------------------------------------------
// MFMA flash attention, exp2 fixed-shift softmax: QK acc C-init = -EXPB so
// the mfma output IS the exp2 argument (scores*log2e - 32*log2e <= 0).
// Paired q-tiles; K/V staged in LDS (4-wave shared, dbuf, chunk-XOR swz).
// ---------------------------------------------------------------------------
__global__ __launch_bounds__(256)
void attn_mfma(const bf16* __restrict__ Qb, const bf16* __restrict__ Kb,
               const bf16* __restrict__ Vt, bf16* __restrict__ O)
{
    __shared__ bf16 kv[2][2][64 * 64];    // [buf][K|V][row*64 + chunk-swizzled]

    int orig   = blockIdx.x;              // 0..1023
    int xcd    = orig & 7;
    int rest   = orig >> 3;               // 0..127
    int bh     = xcd * 8 + (rest & 7);    // 8 (b,h) per XCD -> 4MiB K/V in L2
    int blkraw = rest >> 3;               // 0..15
    int blk    = (blkraw & 1) ? (15 - (blkraw >> 1)) : (blkraw >> 1);
    int w      = threadIdx.x >> 6;        // 0..3
    int pr     = blk * 4 + w;             // 0..63
    int h = bh >> 2, b = bh & 3;

    int lane = threadIdx.x & 63;
    int g = lane >> 4, c = lane & 15;

    const bf16* kbase = Kb + ((long)h * NROW + (long)b * T_) * 64;
    const bf16* vbase = Vt + (long)(h * B_ + b) * 64 * (long)T_;

    int q0A = pr * 16, q0B = (127 - pr) * 16;
    const bf16* qbA = Qb + ((long)h * NROW + (long)b * T_ + q0A) * 64;
    const bf16* qbB = Qb + ((long)h * NROW + (long)b * T_ + q0B) * 64;
    bfrag qfA0 = *(const bfrag*)(qbA + (long)c * 64 + 8 * g);
    bfrag qfA1 = *(const bfrag*)(qbA + (long)c * 64 + 32 + 8 * g);
    bfrag qfB0 = *(const bfrag*)(qbB + (long)c * 64 + 8 * g);
    bfrag qfB1 = *(const bfrag*)(qbB + (long)c * 64 + 32 + 8 * g);

    const f4 CINIT = {-EXPB, -EXPB, -EXPB, -EXPB};

    f4 otA[4] = {{0,0,0,0},{0,0,0,0},{0,0,0,0},{0,0,0,0}};
    f4 otB[4] = {{0,0,0,0},{0,0,0,0},{0,0,0,0},{0,0,0,0}};
    float lA = 0.f, lB = 0.f;

    const int nA = blk, nB = 31 - blk, KT = nB;
    int qgA = q0A + c, qgB = q0B + c;

    const int srow8  = lane >> 3;                 // 0..7
    const int swz    = 8 * ((lane & 7) ^ srow8);  // swizzled source chunk

    auto STAGE = [&](int buf, int kt) {
        int k0 = kt * 64;
#pragma unroll
        for (int i = 0; i < 2; i++) {
            int rb  = (w * 2 + i) * 8;            // row base 0..56
            int row = rb + srow8;
            gl_lds(kbase + (long)(k0 + row) * 64 + swz, &kv[buf][0][rb * 64]);
            gl_lds(vbase + (long)row * T_ + k0 + swz,   &kv[buf][1][rb * 64]);
        }
    };

    STAGE(0, 0);
    __syncthreads();

    const int cx = c & 7;

    for (int kt = 0; kt <= KT; kt++) {
        int buf = kt & 1;
        if (kt < KT) STAGE(buf ^ 1, kt + 1);

        const bf16* Kl = &kv[buf][0][0];
        const bf16* Vl = &kv[buf][1][0];
        int k0 = kt * 64;
        bool actA = (kt <= nA);
        unsigned wvA[8], wvB[8];

#pragma unroll
        for (int kb = 0; kb < 4; kb++) {
            const bf16* kr = Kl + (16 * kb + c) * 64;
            bfrag ka = *(const bfrag*)(kr + 8 * (g ^ cx));
            bfrag kc = *(const bfrag*)(kr + 8 * ((g | 4) ^ cx));

            __builtin_amdgcn_s_setprio(1);
            f4 sB = __builtin_amdgcn_mfma_f32_16x16x32_bf16(ka, qfB0, CINIT, 0, 0, 0);
            sB = __builtin_amdgcn_mfma_f32_16x16x32_bf16(kc, qfB1, sB, 0, 0, 0);
            __builtin_amdgcn_s_setprio(0);
            if (kt == nB) {
#pragma unroll
                for (int r = 0; r < 4; r++)
                    if (k0 + 16 * kb + 4 * g + r > qgB) sB[r] = -1e30f;
            }
            float eB0 = exp2f(sB[0]), eB1 = exp2f(sB[1]);
            float eB2 = exp2f(sB[2]), eB3 = exp2f(sB[3]);
            lB += (eB0 + eB1) + (eB2 + eB3);
            wvB[2 * kb]     = pk2(eB0, eB1);
            wvB[2 * kb + 1] = pk2(eB2, eB3);

            if (actA) {
                __builtin_amdgcn_s_setprio(1);
                f4 sA = __builtin_amdgcn_mfma_f32_16x16x32_bf16(ka, qfA0, CINIT, 0, 0, 0);
                sA = __builtin_amdgcn_mfma_f32_16x16x32_bf16(kc, qfA1, sA, 0, 0, 0);
                __builtin_amdgcn_s_setprio(0);
                if (kt == nA) {
#pragma unroll
                    for (int r = 0; r < 4; r++)
                        if (k0 + 16 * kb + 4 * g + r > qgA) sA[r] = -1e30f;
                }
                float eA0 = exp2f(sA[0]), eA1 = exp2f(sA[1]);
                float eA2 = exp2f(sA[2]), eA3 = exp2f(sA[3]);
                lA += (eA0 + eA1) + (eA2 + eA3);
                wvA[2 * kb]     = pk2(eA0, eA1);
                wvA[2 * kb + 1] = pk2(eA2, eA3);
            }
        }

        // PV: two 32-key halves; B-frag = P^T via lane exchange; V from LDS
#pragma unroll
        for (int p = 0; p < 2; p++) {
            int s0l = c + 32 * (g & 1), s1l = s0l + 16;
            bool hi = (g >= 2);

            unsigned Bb0 = (unsigned)__shfl((int)wvB[4 * p + 0], s0l, 64);
            unsigned Bb1 = (unsigned)__shfl((int)wvB[4 * p + 1], s0l, 64);
            unsigned Bb2 = (unsigned)__shfl((int)wvB[4 * p + 2], s0l, 64);
            unsigned Bb3 = (unsigned)__shfl((int)wvB[4 * p + 3], s0l, 64);
            unsigned Bb4 = (unsigned)__shfl((int)wvB[4 * p + 0], s1l, 64);
            unsigned Bb5 = (unsigned)__shfl((int)wvB[4 * p + 1], s1l, 64);
            unsigned Bb6 = (unsigned)__shfl((int)wvB[4 * p + 2], s1l, 64);
            unsigned Bb7 = (unsigned)__shfl((int)wvB[4 * p + 3], s1l, 64);
            union { bfrag f; unsigned u[4]; } pfB;
            pfB.u[0] = hi ? Bb2 : Bb0;
            pfB.u[1] = hi ? Bb3 : Bb1;
            pfB.u[2] = hi ? Bb6 : Bb4;
            pfB.u[3] = hi ? Bb7 : Bb5;

            union { bfrag f; unsigned u[4]; } pfA;
            if (actA) {
                unsigned Ab0 = (unsigned)__shfl((int)wvA[4 * p + 0], s0l, 64);
                unsigned Ab1 = (unsigned)__shfl((int)wvA[4 * p + 1], s0l, 64);
                unsigned Ab2 = (unsigned)__shfl((int)wvA[4 * p + 2], s0l, 64);
                unsigned Ab3 = (unsigned)__shfl((int)wvA[4 * p + 3], s0l, 64);
                unsigned Ab4 = (unsigned)__shfl((int)wvA[4 * p + 0], s1l, 64);
                unsigned Ab5 = (unsigned)__shfl((int)wvA[4 * p + 1], s1l, 64);
                unsigned Ab6 = (unsigned)__shfl((int)wvA[4 * p + 2], s1l, 64);
                unsigned Ab7 = (unsigned)__shfl((int)wvA[4 * p + 3], s1l, 64);
                pfA.u[0] = hi ? Ab2 : Ab0;
                pfA.u[1] = hi ? Ab3 : Ab1;
                pfA.u[2] = hi ? Ab6 : Ab4;
                pfA.u[3] = hi ? Ab7 : Ab5;
            }

            __builtin_amdgcn_s_setprio(1);
#pragma unroll
            for (int dblk = 0; dblk < 4; dblk++) {
                bfrag vf = *(const bfrag*)(Vl + (16 * dblk + c) * 64
                                              + 8 * (((p << 2) | g) ^ cx));
                otB[dblk] = __builtin_amdgcn_mfma_f32_16x16x32_bf16(vf, pfB.f, otB[dblk], 0, 0, 0);
                if (actA)
                    otA[dblk] = __builtin_amdgcn_mfma_f32_16x16x32_bf16(vf, pfA.f, otA[dblk], 0, 0, 0);
            }
            __builtin_amdgcn_s_setprio(0);
        }
        __syncthreads();
    }

    lA += __shfl_xor(lA, 16, 64); lA += __shfl_xor(lA, 32, 64);
    lB += __shfl_xor(lB, 16, 64); lB += __shfl_xor(lB, 32, 64);

    float invA = 1.f / lA, invB = 1.f / lB;
    long orowA = (long)(b * T_ + q0A + c) * DM + h * 64;
    long orowB = (long)(b * T_ + q0B + c) * DM + h * 64;
#pragma unroll
    for (int dblk = 0; dblk < 4; dblk++)
#pragma unroll
        for (int r = 0; r < 4; r++) {
            O[orowA + 16 * dblk + 4 * g + r] = __float2bfloat16(otA[dblk][r] * invA);
            O[orowB + 16 * dblk + 4 * g + r] = __float2bfloat16(otB[dblk][r] * invB);
        }
}

// ---------------------------------------------------------------------------
template <typename TT>
__global__ __launch_bounds__(256)
void lerp_norm(const float* __restrict__ X, const TT* __restrict__ Tt,
               const float* __restrict__ alpha, float ascale,
               float* __restrict__ Out, bf16* __restrict__ OutB)
{
    long row = blockIdx.x;
    const float* xr = X  + row * DM;
    const TT*    tr = Tt + row * DM;
    int tid = threadIdx.x;

    float xs[4], ts[4], sx = 0.f, st = 0.f;
#pragma unroll
    for (int i = 0; i < 4; i++) {
        int d = tid + 256 * i;
        xs[i] = xr[d]; ts[i] = ldf(&tr[d]);
        sx += xs[i] * xs[i]; st += ts[i] * ts[i];
    }
    sx = block_sum(sx);
    st = block_sum(st);
    float ix = rsqrtf(sx), it = rsqrtf(st);

    float ys[4], sy = 0.f;
#pragma unroll
    for (int i = 0; i < 4; i++) {
        int d = tid + 256 * i;
        float a  = xs[i] * ix;
        float bn = ts[i] * it;
        float lr = fabsf(alpha[d] * ascale);
        ys[i] = a + lr * (bn - a);
        sy += ys[i] * ys[i];
    }
    sy = block_sum(sy);
    float iy = rsqrtf(sy);
#pragma unroll
    for (int i = 0; i < 4; i++) {
        int d = tid + 256 * i;
        float o = ys[i] * iy;
        Out[row * DM + d] = o;
        if (OutB) OutB[row * DM + d] = __float2bfloat16(o);
    }
}

// ---------------------------------------------------------------------------
__global__ __launch_bounds__(256)
void mlp_act(const bf16* __restrict__ UV, const float* __restrict__ suv,
             bf16* __restrict__ R)
{
    long row = blockIdx.x;
    const bf16* ur = UV + row * 8192;
    int tid = threadIdx.x;

    float ss = 0.f;
#pragma unroll
    for (int i = 0; i < 32; i++) {
        int j = tid + 256 * i;
        float v = __bfloat162float(ur[j]) * suv[j] * 32.f;
        ss += v * v;
    }
    ss = block_sum(ss);
    float inv = rsqrtf(ss);

#pragma unroll
    for (int i = 0; i < 16; i++) {
        int j = tid + 256 * i;
        float u = __bfloat162float(ur[j])        * suv[j]        * 32.f * inv;
        float v = __bfloat162float(ur[4096 + j]) * suv[4096 + j] * 32.f * inv;
        float sil = v / (1.f + __expf(-v));
        R[row * 4096 + j] = __float2bfloat16(u * sil);
    }
}

// ---------------------------------------------------------------------------
extern "C" void kernel_launch(void* const* d_in, const int* in_sizes, int n_in,
                              void* d_out, int out_size, void* d_ws, size_t ws_size,
                              hipStream_t stream)
{
    const float* x          = (const float*)d_in[0];
    const float* qkv_w      = (const float*)d_in[1];
    const float* sqk        = (const float*)d_in[2];
    const float* W_O        = (const float*)d_in[3];
    const float* Wu         = (const float*)d_in[4];
    const float* Wv         = (const float*)d_in[5];
    const float* attn_alpha = (const float*)d_in[6];
    const float* mlp_alpha  = (const float*)d_in[7];
    const float* suv        = (const float*)d_in[8];
    float* out = (float*)d_out;

    const long MiB = 1048576;
    char* ws = (char*)d_ws;
    float* x1    = (float*)(ws + 0 * MiB);
    bf16*  x1b   = (bf16*) (ws + 32 * MiB);
    bf16*  QKVb  = (bf16*) (ws + 48 * MiB);
    bf16*  tbuf  = (bf16*) (ws + 48 * MiB);   // 16MB, after QKVb dead
    bf16*  uv    = (bf16*) (ws + 48 * MiB);   // half: [4096][8192]
    bf16*  t2    = (bf16*) (ws + 48 * MiB);   // 16MB, after uv dead
    bf16*  xb    = (bf16*) (ws + 144 * MiB);
    bf16*  Qb    = (bf16*) (ws + 144 * MiB);
    bf16*  Wub   = (bf16*) (ws + 144 * MiB);
    bf16*  Kb    = (bf16*) (ws + 160 * MiB);
    bf16*  Vt    = (bf16*) (ws + 176 * MiB);
    bf16*  Wvb   = (bf16*) (ws + 176 * MiB);
    bf16*  res   = (bf16*) (ws + 112 * MiB);  // [8192][4096]
    bf16*  qkvwb = (bf16*) (ws + 192 * MiB);
    bf16*  attno = (bf16*) (ws + 192 * MiB);
    bf16*  Wob   = (bf16*) (ws + 208 * MiB);
    // peak 210 MiB

    // 0) converts needed before attn
    f32_to_bf16_k<<<4096, 256, 0, stream>>>(x, xb, 8388608L);
    f32_to_bf16_k<<<1536, 256, 0, stream>>>(qkv_w, qkvwb, 3145728L);
    f32_to_bf16_k<<<512,  256, 0, stream>>>(W_O, Wob, 1048576L);

    // 1) QKV projection -> bf16 [8192][3072]  (256^2 4-phase gemm)
    gemm_bf16_256<bf16><<<dim3(12, 32), 512, 0, stream>>>(xb, qkvwb, QKVb, NROW, 3072, DM);

    // 2) RoPE + justnorm + scaling -> Qb/Kb/Vt (Qb carries 32*log2e)
    rope_norm_qk<<<(H_ * NROW) / 4, 256, 0, stream>>>(QKVb, sqk, Qb, Kb, Vt);

    // 3) MFMA flash attention -> attno bf16 (overwrites qkvwb region)
    attn_mfma<<<1024, 256, 0, stream>>>(Qb, Kb, Vt, attno);

    // 4) W_O projection -> tbuf bf16 (QKVb region dead)
    gemm_bf16<bf16><<<dim3(8, 64), 256, 0, stream>>>(attno, Wob, tbuf, NROW, DM, DM);

    // 5) attention residual lerp-norm -> x1 fp32 + x1b bf16
    lerp_norm<bf16><<<NROW, 256, 0, stream>>>(x, tbuf, attn_alpha, 1.6f, x1, x1b);

    // 6) weight converts for MLP (Qb/Kb/Vt dead)
    f32_to_bf16_k<<<4096, 256, 0, stream>>>(Wu, Wub, 8388608L);
    f32_to_bf16_k<<<2048, 256, 0, stream>>>(Wv, Wvb, 4194304L);

    // 7) MLP in two M-halves: uv(half) = x1b @ Wu^T -> bf16; act -> res
    for (int half = 0; half < 2; half++) {
        gemm_bf16_256<bf16><<<dim3(32, 16), 512, 0, stream>>>(
            x1b + (long)half * 4096 * DM, Wub, uv, 4096, 8 * DM, DM);
        mlp_act<<<4096, 256, 0, stream>>>(uv, suv, res + (long)half * 4096 * 4096);
    }
    // note: mlp_act(half2) clobbers Wub region — Wub dead by then.

    // 8) t2 = res @ Wv^T -> bf16 (uv dead)
    gemm_bf16<bf16><<<dim3(8, 64), 256, 0, stream>>>(res, Wvb, t2, NROW, DM, 4 * DM);

    // 9) MLP residual lerp-norm -> out
    lerp_norm<bf16><<<NROW, 256, 0, stream>>>(x1, t2, mlp_alpha, 0.05f, out, (bf16*)nullptr);
}

// Round 10
// 581.902 us; speedup vs baseline: 1.0434x; 1.0434x over previous
//
#include <hip/hip_runtime.h>
#include <hip/hip_bf16.h>

// nGPT-style transformer layer, MI355X. Round 9: revert round-8 regressions
// (libm exp2f -> __builtin_amdgcn_exp2f single v_exp_f32; drop setprio
// toggling; back to 2-cluster 256^2 gemm). Keep exp2 C-init fold + bf16
// tbuf/t2. B=4 T=2048 dm=1024 H=16 di=64.
//
// Workspace arena (peak 210 MiB). Aliasing is ORDER-SENSITIVE; launch order in
// kernel_launch is the contract.

#define B_   4
#define T_   2048
#define DM   1024
#define H_   16
#define DI   64
#define NROW (B_ * T_)   // 8192

using bf16 = __hip_bfloat16;
typedef __attribute__((ext_vector_type(8))) short bfrag;   // 8 bf16 (4 VGPR)
typedef __attribute__((ext_vector_type(4))) float f4;

#define EXPB 46.166241f   // 32 * log2(e): sdpa-scale x log2e, folded into Q

__device__ __forceinline__ float ldf(const float* p) { return *p; }
__device__ __forceinline__ float ldf(const bf16* p)  { return __bfloat162float(*p); }
__device__ __forceinline__ void  stf(float* p, float v) { *p = v; }
__device__ __forceinline__ void  stf(bf16* p, float v)  { *p = __float2bfloat16(v); }

__device__ __forceinline__ unsigned short bfbits(float a) {
    bf16 h = __float2bfloat16(a);
    return __builtin_bit_cast(unsigned short, h);
}
__device__ __forceinline__ unsigned pk2(float a, float b) {
    return (unsigned)bfbits(a) | ((unsigned)bfbits(b) << 16);
}

// fast exp2: single v_exp_f32
__device__ __forceinline__ float fexp2(float x) {
    return __builtin_amdgcn_exp2f(x);
}

__device__ __forceinline__ float wave_sum(float v) {
#pragma unroll
    for (int off = 32; off; off >>= 1) v += __shfl_xor(v, off, 64);
    return v;
}

__device__ __forceinline__ float block_sum(float v) {
    __shared__ float sm[4];
    int lane = threadIdx.x & 63, w = threadIdx.x >> 6;
    v = wave_sum(v);
    __syncthreads();
    if (lane == 0) sm[w] = v;
    __syncthreads();
    return sm[0] + sm[1] + sm[2] + sm[3];
}

// async global->LDS, 16B per lane; LDS dest = wave-uniform base + lane*16
typedef __attribute__((address_space(1))) const void g_void;
typedef __attribute__((address_space(3))) void l_void;
__device__ __forceinline__ void gl_lds(const void* g, void* l) {
    __builtin_amdgcn_global_load_lds((g_void*)g, (l_void*)l, 16, 0, 0);
}

// ---------------------------------------------------------------------------
// f32 -> bf16 convert, 8 elems/thread. n must be a multiple of 2048.
// ---------------------------------------------------------------------------
__global__ __launch_bounds__(256)
void f32_to_bf16_k(const float* __restrict__ in, bf16* __restrict__ out, long n)
{
    long i = ((long)blockIdx.x * 256 + threadIdx.x) * 8;
    if (i >= n) return;
    float4 a = *(const float4*)(in + i);
    float4 b = *(const float4*)(in + i + 4);
    union { bfrag f; unsigned u[4]; } o;
    o.u[0] = pk2(a.x, a.y); o.u[1] = pk2(a.z, a.w);
    o.u[2] = pk2(b.x, b.y); o.u[3] = pk2(b.z, b.w);
    *(bfrag*)(out + i) = o.f;
}

// ---------------------------------------------------------------------------
// C = A * B^T, 128x128 tile, BK=32, 4 waves, m97 structure (N=1024 GEMMs).
// ---------------------------------------------------------------------------
template <typename TC>
__global__ __launch_bounds__(256)
void gemm_bf16(const bf16* __restrict__ A, const bf16* __restrict__ Bm,
               TC* __restrict__ C, int M, int N, int K)
{
    __shared__ bf16 lds[2][2][128 * 32];   // [buf][A|B][row*32+k]
    const int tid  = threadIdx.x;
    const int w    = tid >> 6, lane = tid & 63;
    const int g    = lane >> 4, c = lane & 15;
    const int m0   = blockIdx.y * 128, n0 = blockIdx.x * 128;
    const int wm   = w >> 1, wn = w & 1;

    const int srow = (lane >> 2);        // 0..15 within chunk
    const int skc  = 8 * (lane & 3);     // k elem offset 0,8,16,24

    f4 acc[4][4] = {{{0,0,0,0}}};

    const int NT = K >> 5;               // K/32 steps

#pragma unroll
    for (int q = 0; q < 2; q++) {
        int cidx = w * 2 + q;            // 0..7, covers rows [16*cidx,+16)
        int row  = 16 * cidx + srow;
        gl_lds(A + (long)(m0 + row) * K + skc, &lds[0][0][cidx * 512]);
        gl_lds(Bm + (long)(n0 + row) * K + skc, &lds[0][1][cidx * 512]);
    }
    __syncthreads();

    for (int t = 0; t < NT; t++) {
        int cur = t & 1;
        if (t + 1 < NT) {
            int k0 = (t + 1) << 5;
#pragma unroll
            for (int q = 0; q < 2; q++) {
                int cidx = w * 2 + q;
                int row  = 16 * cidx + srow;
                gl_lds(A + (long)(m0 + row) * K + k0 + skc, &lds[cur ^ 1][0][cidx * 512]);
                gl_lds(Bm + (long)(n0 + row) * K + k0 + skc, &lds[cur ^ 1][1][cidx * 512]);
            }
        }
        const bf16* bufA = &lds[cur][0][0];
        const bf16* bufB = &lds[cur][1][0];
        bfrag af[4], bb[4];
#pragma unroll
        for (int mi = 0; mi < 4; mi++)
            af[mi] = *(const bfrag*)(bufA + (64 * wm + 16 * mi + c) * 32 + 8 * g);
#pragma unroll
        for (int ni = 0; ni < 4; ni++)
            bb[ni] = *(const bfrag*)(bufB + (64 * wn + 16 * ni + c) * 32 + 8 * g);
#pragma unroll
        for (int mi = 0; mi < 4; mi++)
#pragma unroll
            for (int ni = 0; ni < 4; ni++)
                acc[mi][ni] = __builtin_amdgcn_mfma_f32_16x16x32_bf16(
                    af[mi], bb[ni], acc[mi][ni], 0, 0, 0);
        __syncthreads();
    }

#pragma unroll
    for (int mi = 0; mi < 4; mi++)
#pragma unroll
        for (int ni = 0; ni < 4; ni++) {
            long row = m0 + 64 * wm + 16 * mi + 4 * g;
            long col = n0 + 64 * wn + 16 * ni + c;
#pragma unroll
            for (int r = 0; r < 4; r++)
                stf(&C[(row + r) * N + col], acc[mi][ni][r]);
        }
}

// ---------------------------------------------------------------------------
// C = A * B^T, 256x256 tile, BK=64, 8 waves (2M x 4N), 128KB LDS dbuf.
// Round-7 2-cluster schedule: counted vmcnt(8), (row&7) chunk-XOR swizzle,
// setprio around MFMA clusters. M,N %256==0, K %64==0, K>=128.
// ---------------------------------------------------------------------------
template <typename TC>
__global__ __launch_bounds__(512, 2)
void gemm_bf16_256(const bf16* __restrict__ A, const bf16* __restrict__ Bm,
                   TC* __restrict__ C, int M, int N, int K)
{
    __shared__ bf16 lds[2][2][256 * 64];   // 128 KiB
    const int tid  = threadIdx.x;
    const int w    = tid >> 6, lane = tid & 63;
    const int g    = lane >> 4, c = lane & 15;
    const int m0   = blockIdx.y * 256, n0 = blockIdx.x * 256;
    const int wm   = w & 1, wn = w >> 1;          // 2M x 4N wave grid
    const int srow8 = lane >> 3;                  // 0..7
    const int swz   = 8 * ((lane & 7) ^ srow8);   // pre-swizzled source chunk
    const int cx    = c & 7;

    f4 acc[8][4] = {{{0,0,0,0}}};

    const int NT = K >> 6;

    auto STAGE = [&](int buf, int t) {
        int k0 = t << 6;
#pragma unroll
        for (int i = 0; i < 4; i++) {
            int rb = w * 32 + i * 8;              // 8 rows per gl_lds
            gl_lds(A  + (long)(m0 + rb + srow8) * K + k0 + swz, &lds[buf][0][rb * 64]);
            gl_lds(Bm + (long)(n0 + rb + srow8) * K + k0 + swz, &lds[buf][1][rb * 64]);
        }
    };

    STAGE(0, 0);
    STAGE(1, 1);
    asm volatile("s_waitcnt vmcnt(8)" ::: "memory");
    __builtin_amdgcn_s_barrier();

    for (int t = 0; t < NT; t++) {
        const bf16* bufA = &lds[t & 1][0][0];
        const bf16* bufB = &lds[t & 1][1][0];

        bfrag a0[4][2], b0[4][2];
#pragma unroll
        for (int mi = 0; mi < 4; mi++)
#pragma unroll
            for (int kk = 0; kk < 2; kk++)
                a0[mi][kk] = *(const bfrag*)(bufA + (wm * 128 + mi * 16 + c) * 64
                                                  + 8 * ((4 * kk + g) ^ cx));
#pragma unroll
        for (int ni = 0; ni < 4; ni++)
#pragma unroll
            for (int kk = 0; kk < 2; kk++)
                b0[ni][kk] = *(const bfrag*)(bufB + (wn * 64 + ni * 16 + c) * 64
                                                  + 8 * ((4 * kk + g) ^ cx));
        asm volatile("s_waitcnt lgkmcnt(0)" ::: "memory");
        __builtin_amdgcn_sched_barrier(0);
        __builtin_amdgcn_s_setprio(1);
#pragma unroll
        for (int mi = 0; mi < 4; mi++)
#pragma unroll
            for (int ni = 0; ni < 4; ni++) {
                acc[mi][ni] = __builtin_amdgcn_mfma_f32_16x16x32_bf16(
                    a0[mi][0], b0[ni][0], acc[mi][ni], 0, 0, 0);
                acc[mi][ni] = __builtin_amdgcn_mfma_f32_16x16x32_bf16(
                    a0[mi][1], b0[ni][1], acc[mi][ni], 0, 0, 0);
            }
        __builtin_amdgcn_s_setprio(0);

        bfrag a1[4][2];
#pragma unroll
        for (int mi = 0; mi < 4; mi++)
#pragma unroll
            for (int kk = 0; kk < 2; kk++)
                a1[mi][kk] = *(const bfrag*)(bufA + (wm * 128 + (mi + 4) * 16 + c) * 64
                                                  + 8 * ((4 * kk + g) ^ cx));
        asm volatile("s_waitcnt lgkmcnt(0)" ::: "memory");
        __builtin_amdgcn_sched_barrier(0);
        __builtin_amdgcn_s_setprio(1);
#pragma unroll
        for (int mi = 0; mi < 4; mi++)
#pragma unroll
            for (int ni = 0; ni < 4; ni++) {
                acc[mi + 4][ni] = __builtin_amdgcn_mfma_f32_16x16x32_bf16(
                    a1[mi][0], b0[ni][0], acc[mi + 4][ni], 0, 0, 0);
                acc[mi + 4][ni] = __builtin_amdgcn_mfma_f32_16x16x32_bf16(
                    a1[mi][1], b0[ni][1], acc[mi + 4][ni], 0, 0, 0);
            }
        __builtin_amdgcn_s_setprio(0);

        __builtin_amdgcn_s_barrier();
        if (t + 2 < NT) {
            STAGE(t & 1, t + 2);
            asm volatile("s_waitcnt vmcnt(8)" ::: "memory");
        } else if (t + 1 < NT) {
            asm volatile("s_waitcnt vmcnt(0)" ::: "memory");
        }
        __builtin_amdgcn_s_barrier();
    }

#pragma unroll
    for (int mi = 0; mi < 8; mi++)
#pragma unroll
        for (int ni = 0; ni < 4; ni++) {
            long row = m0 + wm * 128 + mi * 16 + 4 * g;
            long col = n0 + wn * 64 + ni * 16 + c;
#pragma unroll
            for (int r = 0; r < 4; r++)
                stf(&C[(row + r) * N + col], acc[mi][ni][r]);
        }
}

// ---------------------------------------------------------------------------
// RoPE + per-row L2 norm + sqk*sqrt(dm); QKVb bf16 layout [row][h*192+e].
// Qb carries sdpa sqrt(dm)=32 AND log2e (exp2 path in attn).
// ---------------------------------------------------------------------------
__global__ __launch_bounds__(256)
void rope_norm_qk(const bf16* __restrict__ QKVb, const float* __restrict__ sqk,
                  bf16* __restrict__ Qb, bf16* __restrict__ Kb, bf16* __restrict__ Vt)
{
    int gw   = (blockIdx.x * 256 + threadIdx.x) >> 6;   // 0 .. H*NROW-1
    int lane = threadIdx.x & 63;
    int h = gw / NROW, row = gw % NROW, t = row % T_, b = row / T_;

    const bf16* base = QKVb + (long)row * 3072 + h * 192;
    float q = __bfloat162float(base[lane]);
    float k = __bfloat162float(base[64 + lane]);
    bf16  v = base[128 + lane];

    int   j   = lane & 31;
    float inv = expf(-(float)j * (9.210340371976184f / 32.f));  // 10000^(-j/32)
    float ang = (float)t * inv;
    float s = sinf(ang), cc = cosf(ang);

    float qp = __shfl_xor(q, 32, 64);
    float kp = __shfl_xor(k, 32, 64);
    float sgn = (lane < 32) ? -1.f : 1.f;
    float qr = q * cc + sgn * qp * s;
    float kr = k * cc + sgn * kp * s;

    float qs = wave_sum(qr * qr);
    float ks = wave_sum(kr * kr);
    float se = sqk[h * 64 + lane] * 32.f;   // sqk * sqrt(dm)

    long idx = ((long)h * NROW + row) * 64 + lane;
    Qb[idx] = __float2bfloat16(qr * rsqrtf(qs) * se * EXPB);  // 32*log2e folded
    Kb[idx] = __float2bfloat16(kr * rsqrtf(ks) * se);
    Vt[((long)(h * B_ + b) * 64 + lane) * T_ + t] = v;
}

// ---------------------------------------------------------------------------
// MFMA flash attention, exp2 fixed-shift softmax (C-init = -EXPB), paired
// q-tiles, K/V staged in LDS (4-wave shared, dbuf, chunk-XOR swizzled).
// Round-7 structure; exp = single v_exp_f32; no setprio.
// ---------------------------------------------------------------------------
__global__ __launch_bounds__(256)
void attn_mfma(const bf16* __restrict__ Qb, const bf16* __restrict__ Kb,
               const bf16* __restrict__ Vt, bf16* __restrict__ O)
{
    __shared__ bf16 kv[2][2][64 * 64];    // [buf][K|V][row*64 + chunk-swizzled]

    int orig   = blockIdx.x;              // 0..1023
    int xcd    = orig & 7;
    int rest   = orig >> 3;               // 0..127
    int bh     = xcd * 8 + (rest & 7);    // 8 (b,h) per XCD -> 4MiB K/V in L2
    int blkraw = rest >> 3;               // 0..15
    int blk    = (blkraw & 1) ? (15 - (blkraw >> 1)) : (blkraw >> 1);
    int w      = threadIdx.x >> 6;        // 0..3
    int pr     = blk * 4 + w;             // 0..63
    int h = bh >> 2, b = bh & 3;

    int lane = threadIdx.x & 63;
    int g = lane >> 4, c = lane & 15;

    const bf16* kbase = Kb + ((long)h * NROW + (long)b * T_) * 64;
    const bf16* vbase = Vt + (long)(h * B_ + b) * 64 * (long)T_;

    int q0A = pr * 16, q0B = (127 - pr) * 16;
    const bf16* qbA = Qb + ((long)h * NROW + (long)b * T_ + q0A) * 64;
    const bf16* qbB = Qb + ((long)h * NROW + (long)b * T_ + q0B) * 64;
    bfrag qfA0 = *(const bfrag*)(qbA + (long)c * 64 + 8 * g);
    bfrag qfA1 = *(const bfrag*)(qbA + (long)c * 64 + 32 + 8 * g);
    bfrag qfB0 = *(const bfrag*)(qbB + (long)c * 64 + 8 * g);
    bfrag qfB1 = *(const bfrag*)(qbB + (long)c * 64 + 32 + 8 * g);

    const f4 CINIT = {-EXPB, -EXPB, -EXPB, -EXPB};

    f4 otA[4] = {{0,0,0,0},{0,0,0,0},{0,0,0,0},{0,0,0,0}};
    f4 otB[4] = {{0,0,0,0},{0,0,0,0},{0,0,0,0},{0,0,0,0}};
    float lA = 0.f, lB = 0.f;

    const int nA = blk, nB = 31 - blk, KT = nB;
    int qgA = q0A + c, qgB = q0B + c;

    const int srow8  = lane >> 3;                 // 0..7
    const int swz    = 8 * ((lane & 7) ^ srow8);  // swizzled source chunk

    auto STAGE = [&](int buf, int kt) {
        int k0 = kt * 64;
#pragma unroll
        for (int i = 0; i < 2; i++) {
            int rb  = (w * 2 + i) * 8;            // row base 0..56
            int row = rb + srow8;
            gl_lds(kbase + (long)(k0 + row) * 64 + swz, &kv[buf][0][rb * 64]);
            gl_lds(vbase + (long)row * T_ + k0 + swz,   &kv[buf][1][rb * 64]);
        }
    };

    STAGE(0, 0);
    __syncthreads();

    const int cx = c & 7;

    for (int kt = 0; kt <= KT; kt++) {
        int buf = kt & 1;
        if (kt < KT) STAGE(buf ^ 1, kt + 1);

        const bf16* Kl = &kv[buf][0][0];
        const bf16* Vl = &kv[buf][1][0];
        int k0 = kt * 64;
        bool actA = (kt <= nA);
        unsigned wvA[8], wvB[8];

#pragma unroll
        for (int kb = 0; kb < 4; kb++) {
            const bf16* kr = Kl + (16 * kb + c) * 64;
            bfrag ka = *(const bfrag*)(kr + 8 * (g ^ cx));
            bfrag kc = *(const bfrag*)(kr + 8 * ((g | 4) ^ cx));

            f4 sB = __builtin_amdgcn_mfma_f32_16x16x32_bf16(ka, qfB0, CINIT, 0, 0, 0);
            sB = __builtin_amdgcn_mfma_f32_16x16x32_bf16(kc, qfB1, sB, 0, 0, 0);
            if (kt == nB) {
#pragma unroll
                for (int r = 0; r < 4; r++)
                    if (k0 + 16 * kb + 4 * g + r > qgB) sB[r] = -1e30f;
            }
            float eB0 = fexp2(sB[0]), eB1 = fexp2(sB[1]);
            float eB2 = fexp2(sB[2]), eB3 = fexp2(sB[3]);
            lB += (eB0 + eB1) + (eB2 + eB3);
            wvB[2 * kb]     = pk2(eB0, eB1);
            wvB[2 * kb + 1] = pk2(eB2, eB3);

            if (actA) {
                f4 sA = __builtin_amdgcn_mfma_f32_16x16x32_bf16(ka, qfA0, CINIT, 0, 0, 0);
                sA = __builtin_amdgcn_mfma_f32_16x16x32_bf16(kc, qfA1, sA, 0, 0, 0);
                if (kt == nA) {
#pragma unroll
                    for (int r = 0; r < 4; r++)
                        if (k0 + 16 * kb + 4 * g + r > qgA) sA[r] = -1e30f;
                }
                float eA0 = fexp2(sA[0]), eA1 = fexp2(sA[1]);
                float eA2 = fexp2(sA[2]), eA3 = fexp2(sA[3]);
                lA += (eA0 + eA1) + (eA2 + eA3);
                wvA[2 * kb]     = pk2(eA0, eA1);
                wvA[2 * kb + 1] = pk2(eA2, eA3);
            }
        }

        // PV: two 32-key halves; B-frag = P^T via lane exchange; V from LDS
#pragma unroll
        for (int p = 0; p < 2; p++) {
            int s0l = c + 32 * (g & 1), s1l = s0l + 16;
            bool hi = (g >= 2);

            unsigned Bb0 = (unsigned)__shfl((int)wvB[4 * p + 0], s0l, 64);
            unsigned Bb1 = (unsigned)__shfl((int)wvB[4 * p + 1], s0l, 64);
            unsigned Bb2 = (unsigned)__shfl((int)wvB[4 * p + 2], s0l, 64);
            unsigned Bb3 = (unsigned)__shfl((int)wvB[4 * p + 3], s0l, 64);
            unsigned Bb4 = (unsigned)__shfl((int)wvB[4 * p + 0], s1l, 64);
            unsigned Bb5 = (unsigned)__shfl((int)wvB[4 * p + 1], s1l, 64);
            unsigned Bb6 = (unsigned)__shfl((int)wvB[4 * p + 2], s1l, 64);
            unsigned Bb7 = (unsigned)__shfl((int)wvB[4 * p + 3], s1l, 64);
            union { bfrag f; unsigned u[4]; } pfB;
            pfB.u[0] = hi ? Bb2 : Bb0;
            pfB.u[1] = hi ? Bb3 : Bb1;
            pfB.u[2] = hi ? Bb6 : Bb4;
            pfB.u[3] = hi ? Bb7 : Bb5;

            union { bfrag f; unsigned u[4]; } pfA;
            if (actA) {
                unsigned Ab0 = (unsigned)__shfl((int)wvA[4 * p + 0], s0l, 64);
                unsigned Ab1 = (unsigned)__shfl((int)wvA[4 * p + 1], s0l, 64);
                unsigned Ab2 = (unsigned)__shfl((int)wvA[4 * p + 2], s0l, 64);
                unsigned Ab3 = (unsigned)__shfl((int)wvA[4 * p + 3], s0l, 64);
                unsigned Ab4 = (unsigned)__shfl((int)wvA[4 * p + 0], s1l, 64);
                unsigned Ab5 = (unsigned)__shfl((int)wvA[4 * p + 1], s1l, 64);
                unsigned Ab6 = (unsigned)__shfl((int)wvA[4 * p + 2], s1l, 64);
                unsigned Ab7 = (unsigned)__shfl((int)wvA[4 * p + 3], s1l, 64);
                pfA.u[0] = hi ? Ab2 : Ab0;
                pfA.u[1] = hi ? Ab3 : Ab1;
                pfA.u[2] = hi ? Ab6 : Ab4;
                pfA.u[3] = hi ? Ab7 : Ab5;
            }

#pragma unroll
            for (int dblk = 0; dblk < 4; dblk++) {
                bfrag vf = *(const bfrag*)(Vl + (16 * dblk + c) * 64
                                              + 8 * (((p << 2) | g) ^ cx));
                otB[dblk] = __builtin_amdgcn_mfma_f32_16x16x32_bf16(vf, pfB.f, otB[dblk], 0, 0, 0);
                if (actA)
                    otA[dblk] = __builtin_amdgcn_mfma_f32_16x16x32_bf16(vf, pfA.f, otA[dblk], 0, 0, 0);
            }
        }
        __syncthreads();
    }

    lA += __shfl_xor(lA, 16, 64); lA += __shfl_xor(lA, 32, 64);
    lB += __shfl_xor(lB, 16, 64); lB += __shfl_xor(lB, 32, 64);

    float invA = 1.f / lA, invB = 1.f / lB;
    long orowA = (long)(b * T_ + q0A + c) * DM + h * 64;
    long orowB = (long)(b * T_ + q0B + c) * DM + h * 64;
#pragma unroll
    for (int dblk = 0; dblk < 4; dblk++)
#pragma unroll
        for (int r = 0; r < 4; r++) {
            O[orowA + 16 * dblk + 4 * g + r] = __float2bfloat16(otA[dblk][r] * invA);
            O[orowB + 16 * dblk + 4 * g + r] = __float2bfloat16(otB[dblk][r] * invB);
        }
}

// ---------------------------------------------------------------------------
template <typename TT>
__global__ __launch_bounds__(256)
void lerp_norm(const float* __restrict__ X, const TT* __restrict__ Tt,
               const float* __restrict__ alpha, float ascale,
               float* __restrict__ Out, bf16* __restrict__ OutB)
{
    long row = blockIdx.x;
    const float* xr = X  + row * DM;
    const TT*    tr = Tt + row * DM;
    int tid = threadIdx.x;

    float xs[4], ts[4], sx = 0.f, st = 0.f;
#pragma unroll
    for (int i = 0; i < 4; i++) {
        int d = tid + 256 * i;
        xs[i] = xr[d]; ts[i] = ldf(&tr[d]);
        sx += xs[i] * xs[i]; st += ts[i] * ts[i];
    }
    sx = block_sum(sx);
    st = block_sum(st);
    float ix = rsqrtf(sx), it = rsqrtf(st);

    float ys[4], sy = 0.f;
#pragma unroll
    for (int i = 0; i < 4; i++) {
        int d = tid + 256 * i;
        float a  = xs[i] * ix;
        float bn = ts[i] * it;
        float lr = fabsf(alpha[d] * ascale);
        ys[i] = a + lr * (bn - a);
        sy += ys[i] * ys[i];
    }
    sy = block_sum(sy);
    float iy = rsqrtf(sy);
#pragma unroll
    for (int i = 0; i < 4; i++) {
        int d = tid + 256 * i;
        float o = ys[i] * iy;
        Out[row * DM + d] = o;
        if (OutB) OutB[row * DM + d] = __float2bfloat16(o);
    }
}

// ---------------------------------------------------------------------------
__global__ __launch_bounds__(256)
void mlp_act(const bf16* __restrict__ UV, const float* __restrict__ suv,
             bf16* __restrict__ R)
{
    long row = blockIdx.x;
    const bf16* ur = UV + row * 8192;
    int tid = threadIdx.x;

    float ss = 0.f;
#pragma unroll
    for (int i = 0; i < 32; i++) {
        int j = tid + 256 * i;
        float v = __bfloat162float(ur[j]) * suv[j] * 32.f;
        ss += v * v;
    }
    ss = block_sum(ss);
    float inv = rsqrtf(ss);

#pragma unroll
    for (int i = 0; i < 16; i++) {
        int j = tid + 256 * i;
        float u = __bfloat162float(ur[j])        * suv[j]        * 32.f * inv;
        float v = __bfloat162float(ur[4096 + j]) * suv[4096 + j] * 32.f * inv;
        float sil = v / (1.f + __expf(-v));
        R[row * 4096 + j] = __float2bfloat16(u * sil);
    }
}

// ---------------------------------------------------------------------------
extern "C" void kernel_launch(void* const* d_in, const int* in_sizes, int n_in,
                              void* d_out, int out_size, void* d_ws, size_t ws_size,
                              hipStream_t stream)
{
    const float* x          = (const float*)d_in[0];
    const float* qkv_w      = (const float*)d_in[1];
    const float* sqk        = (const float*)d_in[2];
    const float* W_O        = (const float*)d_in[3];
    const float* Wu         = (const float*)d_in[4];
    const float* Wv         = (const float*)d_in[5];
    const float* attn_alpha = (const float*)d_in[6];
    const float* mlp_alpha  = (const float*)d_in[7];
    const float* suv        = (const float*)d_in[8];
    float* out = (float*)d_out;

    const long MiB = 1048576;
    char* ws = (char*)d_ws;
    float* x1    = (float*)(ws + 0 * MiB);
    bf16*  x1b   = (bf16*) (ws + 32 * MiB);
    bf16*  QKVb  = (bf16*) (ws + 48 * MiB);
    bf16*  tbuf  = (bf16*) (ws + 48 * MiB);   // 16MB, after QKVb dead
    bf16*  uv    = (bf16*) (ws + 48 * MiB);   // half: [4096][8192]
    bf16*  t2    = (bf16*) (ws + 48 * MiB);   // 16MB, after uv dead
    bf16*  xb    = (bf16*) (ws + 144 * MiB);
    bf16*  Qb    = (bf16*) (ws + 144 * MiB);
    bf16*  Wub   = (bf16*) (ws + 144 * MiB);
    bf16*  Kb    = (bf16*) (ws + 160 * MiB);
    bf16*  Vt    = (bf16*) (ws + 176 * MiB);
    bf16*  Wvb   = (bf16*) (ws + 176 * MiB);
    bf16*  res   = (bf16*) (ws + 112 * MiB);  // [8192][4096]
    bf16*  qkvwb = (bf16*) (ws + 192 * MiB);
    bf16*  attno = (bf16*) (ws + 192 * MiB);
    bf16*  Wob   = (bf16*) (ws + 208 * MiB);
    // peak 210 MiB

    // 0) converts needed before attn
    f32_to_bf16_k<<<4096, 256, 0, stream>>>(x, xb, 8388608L);
    f32_to_bf16_k<<<1536, 256, 0, stream>>>(qkv_w, qkvwb, 3145728L);
    f32_to_bf16_k<<<512,  256, 0, stream>>>(W_O, Wob, 1048576L);

    // 1) QKV projection -> bf16 [8192][3072]  (256^2 pipelined gemm)
    gemm_bf16_256<bf16><<<dim3(12, 32), 512, 0, stream>>>(xb, qkvwb, QKVb, NROW, 3072, DM);

    // 2) RoPE + justnorm + scaling -> Qb/Kb/Vt (Qb carries 32*log2e)
    rope_norm_qk<<<(H_ * NROW) / 4, 256, 0, stream>>>(QKVb, sqk, Qb, Kb, Vt);

    // 3) MFMA flash attention -> attno bf16 (overwrites qkvwb region)
    attn_mfma<<<1024, 256, 0, stream>>>(Qb, Kb, Vt, attno);

    // 4) W_O projection -> tbuf bf16 (QKVb region dead)
    gemm_bf16<bf16><<<dim3(8, 64), 256, 0, stream>>>(attno, Wob, tbuf, NROW, DM, DM);

    // 5) attention residual lerp-norm -> x1 fp32 + x1b bf16
    lerp_norm<bf16><<<NROW, 256, 0, stream>>>(x, tbuf, attn_alpha, 1.6f, x1, x1b);

    // 6) weight converts for MLP (Qb/Kb/Vt dead)
    f32_to_bf16_k<<<4096, 256, 0, stream>>>(Wu, Wub, 8388608L);
    f32_to_bf16_k<<<2048, 256, 0, stream>>>(Wv, Wvb, 4194304L);

    // 7) MLP in two M-halves: uv(half) = x1b @ Wu^T -> bf16; act -> res
    for (int half = 0; half < 2; half++) {
        gemm_bf16_256<bf16><<<dim3(32, 16), 512, 0, stream>>>(
            x1b + (long)half * 4096 * DM, Wub, uv, 4096, 8 * DM, DM);
        mlp_act<<<4096, 256, 0, stream>>>(uv, suv, res + (long)half * 4096 * 4096);
    }
    // note: mlp_act(half2) clobbers Wub region — Wub dead by then.

    // 8) t2 = res @ Wv^T -> bf16 (uv dead)
    gemm_bf16<bf16><<<dim3(8, 64), 256, 0, stream>>>(res, Wvb, t2, NROW, DM, 4 * DM);

    // 9) MLP residual lerp-norm -> out
    lerp_norm<bf16><<<NROW, 256, 0, stream>>>(x1, t2, mlp_alpha, 0.05f, out, (bf16*)nullptr);
}